// Round 1
// baseline (581.856 us; speedup 1.0000x reference)
//
#include <hip/hip_runtime.h>
#include <hip/hip_bf16.h>

typedef float f32x4 __attribute__((ext_vector_type(4)));
typedef __bf16 bf16x8 __attribute__((ext_vector_type(8)));
typedef __bf16 bf16x4 __attribute__((ext_vector_type(4)));

#define S_LEN 2048
#define NHEADS 16
#define HDIM 128
// SCALE * log2(e): softmax computed in exp2 domain
#define KLOG2E (0.08838834764831845f * 1.4426950408889634f)

__device__ __forceinline__ void gld_lds16(const __bf16* g, __bf16* l) {
  __builtin_amdgcn_global_load_lds(
      (__attribute__((address_space(1))) void*)(void*)g,
      (__attribute__((address_space(3))) void*)l,
      16, 0, 0);
}

// ---------------------------------------------------------------- conversions
__global__ __launch_bounds__(256) void cvt_f32_bf16(const float* __restrict__ in,
                                                    __bf16* __restrict__ out, int n) {
  int i = (blockIdx.x * 256 + threadIdx.x) * 4;
  if (i >= n) return;
  float4 v = *(const float4*)(in + i);
  bf16x4 o;
  o[0] = (__bf16)v.x; o[1] = (__bf16)v.y; o[2] = (__bf16)v.z; o[3] = (__bf16)v.w;
  *(bf16x4*)(out + i) = o;
}

// ---------------------------------------------------------------- RoPE (in-place on q,k heads)
__global__ __launch_bounds__(256) void rope_kernel(__bf16* __restrict__ qkv,
                                                   const float* __restrict__ cosp,
                                                   const float* __restrict__ sinp) {
  int t = blockIdx.x * 256 + threadIdx.x;   // 0 .. 8388607
  int d = t & 63;
  int head = (t >> 6) & 31;                 // 0..15 q, 16..31 k
  int s = (t >> 11) & 2047;
  int b = t >> 22;
  int base = ((b * S_LEN + s) * 48 + head) * HDIM;
  float x1 = (float)qkv[base + d];
  float x2 = (float)qkv[base + d + 64];
  float c1 = cosp[s * HDIM + d],      s1 = sinp[s * HDIM + d];
  float c2 = cosp[s * HDIM + d + 64], s2 = sinp[s * HDIM + d + 64];
  qkv[base + d]      = (__bf16)(x1 * c1 - x2 * s1);
  qkv[base + d + 64] = (__bf16)(x2 * c2 + x1 * s2);
}

// ---------------------------------------------------------------- GEMM: C[m][n] = sum_k A[m][k]*B[n][k]
// m97-style: 128x128 tile, BK=32, 4 waves (2x2), global_load_lds width 16.
template <typename OutT>
__global__ __launch_bounds__(256)
void gemm_bt(const __bf16* __restrict__ A, const __bf16* __restrict__ B,
             OutT* __restrict__ C, int M, int N, int K) {
  __shared__ alignas(16) __bf16 As[128 * 32];
  __shared__ alignas(16) __bf16 Bs[128 * 32];
  const int tid = threadIdx.x;
  const int lane = tid & 63;
  const int w = tid >> 6;
  const int l15 = lane & 15, quad = lane >> 4;
  const int wm = w >> 1, wn = w & 1;
  const int am0 = blockIdx.y * 128;
  const int bn0 = blockIdx.x * 128;
  f32x4 acc[4][4] = {};
  const int c0 = tid, c1 = tid + 256;
  const int ar0 = c0 >> 2, ac0 = (c0 & 3) * 8;
  const int ar1 = c1 >> 2, ac1 = (c1 & 3) * 8;
  for (int k0 = 0; k0 < K; k0 += 32) {
    gld_lds16(A + (am0 + ar0) * K + k0 + ac0, As + c0 * 8);
    gld_lds16(A + (am0 + ar1) * K + k0 + ac1, As + c1 * 8);
    gld_lds16(B + (bn0 + ar0) * K + k0 + ac0, Bs + c0 * 8);
    gld_lds16(B + (bn0 + ar1) * K + k0 + ac1, Bs + c1 * 8);
    __syncthreads();
    bf16x8 af[4], bfr[4];
#pragma unroll
    for (int i = 0; i < 4; ++i)
      af[i] = *(const bf16x8*)(As + (wm * 64 + i * 16 + l15) * 32 + quad * 8);
#pragma unroll
    for (int i = 0; i < 4; ++i)
      bfr[i] = *(const bf16x8*)(Bs + (wn * 64 + i * 16 + l15) * 32 + quad * 8);
#pragma unroll
    for (int i = 0; i < 4; ++i)
#pragma unroll
      for (int j = 0; j < 4; ++j)
        acc[i][j] = __builtin_amdgcn_mfma_f32_16x16x32_bf16(af[i], bfr[j], acc[i][j], 0, 0, 0);
    __syncthreads();
  }
  // C/D layout: col = lane&15, row = quad*4 + reg  [m89-verified]
#pragma unroll
  for (int i = 0; i < 4; ++i) {
    const int row_b = am0 + wm * 64 + i * 16 + quad * 4;
#pragma unroll
    for (int j = 0; j < 4; ++j) {
      const int col = bn0 + wn * 64 + j * 16 + l15;
#pragma unroll
      for (int r = 0; r < 4; ++r)
        C[(row_b + r) * N + col] = (OutT)acc[i][j][r];
    }
  }
}

// ---------------------------------------------------------------- flash attention
// grid = (32 q-tiles, 32 b*h); block = 256 (4 waves); BM=64 (16 q-rows/wave), BN=64 keys/iter.
__global__ __launch_bounds__(256)
void attn_kernel(const __bf16* __restrict__ qkv, __bf16* __restrict__ O) {
  const int qt = blockIdx.x;
  const int bh = blockIdx.y;
  const int b = bh >> 4, h = bh & 15;
  const int tid = threadIdx.x;
  const int w = tid >> 6;
  const int lane = tid & 63;
  const int l15 = lane & 15, quad = lane >> 4;

  __shared__ alignas(16) __bf16 Qs[4][64][32];   // 16 KB, d-chunked
  __shared__ alignas(16) __bf16 Ks[4][64][32];   // 16 KB, d-chunked
  __shared__ alignas(16) __bf16 Vt[128][72];     // 18 KB, V^T [d][key], +8 pad
  __shared__ alignas(16) __bf16 Ps[4][16][72];   // 9 KB, per-wave P, +8 pad

  // ---- stage Q once (wave w stages d-chunk w)
#pragma unroll
  for (int ii = 0; ii < 4; ++ii) {
    int ci = ii * 64 + lane;                     // 0..255 16B-chunks
    int row = ci >> 2, c8 = (ci & 3) * 8;
    gld_lds16(qkv + ((b * S_LEN + qt * 64 + row) * 48 + h) * HDIM + w * 32 + c8,
              &Qs[w][0][0] + ci * 8);
  }

  f32x4 o_acc[8] = {};
  float m_i[4], l_i[4];
#pragma unroll
  for (int r = 0; r < 4; ++r) { m_i[r] = -3.0e38f; l_i[r] = 0.f; }

  for (int j0 = 0; j0 < S_LEN; j0 += 64) {
    // ---- stage K (wave w stages d-chunk w)
#pragma unroll
    for (int ii = 0; ii < 4; ++ii) {
      int ci = ii * 64 + lane;
      int row = ci >> 2, c8 = (ci & 3) * 8;
      gld_lds16(qkv + ((b * S_LEN + j0 + row) * 48 + 16 + h) * HDIM + w * 32 + c8,
                &Ks[w][0][0] + ci * 8);
    }
    // ---- stage V transposed: lane = key column j, wave w covers d = w*32..w*32+31
    {
      const int j = lane;
      const int dbase = w * 32;
      const __bf16* g = qkv + ((b * S_LEN + j0 + j) * 48 + 32 + h) * HDIM + dbase;
#pragma unroll
      for (int i = 0; i < 4; ++i) {
        bf16x8 v = *(const bf16x8*)(g + i * 8);
#pragma unroll
        for (int e = 0; e < 8; ++e) Vt[dbase + i * 8 + e][j] = v[e];
      }
    }
    __syncthreads();

    // ---- QK^T: 16 q-rows x 64 keys per wave
    f32x4 sc[4] = {};
#pragma unroll
    for (int kk = 0; kk < 4; ++kk) {
      bf16x8 a = *(const bf16x8*)&Qs[kk][w * 16 + l15][quad * 8];
#pragma unroll
      for (int t = 0; t < 4; ++t) {
        bf16x8 bb = *(const bf16x8*)&Ks[kk][t * 16 + l15][quad * 8];
        sc[t] = __builtin_amdgcn_mfma_f32_16x16x32_bf16(a, bb, sc[t], 0, 0, 0);
      }
    }

    // ---- online softmax (rows = quad*4+reg; cols spread over 16-lane group x 4 tiles)
    float mp[4];
#pragma unroll
    for (int r = 0; r < 4; ++r)
      mp[r] = fmaxf(fmaxf(sc[0][r], sc[1][r]), fmaxf(sc[2][r], sc[3][r]));
#pragma unroll
    for (int off = 1; off < 16; off <<= 1)
#pragma unroll
      for (int r = 0; r < 4; ++r)
        mp[r] = fmaxf(mp[r], __shfl_xor(mp[r], off, 16));

    float al[4];
#pragma unroll
    for (int r = 0; r < 4; ++r) {
      float m_new = fmaxf(m_i[r], mp[r] * KLOG2E);
      al[r] = exp2f(m_i[r] - m_new);
      m_i[r] = m_new;
    }
    float rsum[4] = {0.f, 0.f, 0.f, 0.f};
#pragma unroll
    for (int t = 0; t < 4; ++t)
#pragma unroll
      for (int r = 0; r < 4; ++r) {
        float p = exp2f(sc[t][r] * KLOG2E - m_i[r]);
        rsum[r] += p;
        Ps[w][quad * 4 + r][t * 16 + l15] = (__bf16)p;   // C-layout -> LDS
      }
#pragma unroll
    for (int off = 1; off < 16; off <<= 1)
#pragma unroll
      for (int r = 0; r < 4; ++r) rsum[r] += __shfl_xor(rsum[r], off, 16);
#pragma unroll
    for (int r = 0; r < 4; ++r) l_i[r] = l_i[r] * al[r] + rsum[r];
#pragma unroll
    for (int t = 0; t < 8; ++t)
#pragma unroll
      for (int r = 0; r < 4; ++r) o_acc[t][r] *= al[r];

    __syncthreads();   // Ps visible (same-wave DS order paranoia; cheap)

    // ---- PV: P (A-layout from Ps) x V (B-operand from Vt = V^T)
#pragma unroll
    for (int kk = 0; kk < 2; ++kk) {
      bf16x8 a = *(const bf16x8*)&Ps[w][l15][kk * 32 + quad * 8];
#pragma unroll
      for (int t = 0; t < 8; ++t) {
        bf16x8 bb = *(const bf16x8*)&Vt[t * 16 + l15][kk * 32 + quad * 8];
        o_acc[t] = __builtin_amdgcn_mfma_f32_16x16x32_bf16(a, bb, o_acc[t], 0, 0, 0);
      }
    }
    __syncthreads();   // done with Ks/Vt before next stage
  }

  // ---- epilogue: normalize, store O[b][row][h*128 + d] as bf16
  float inv[4];
#pragma unroll
  for (int r = 0; r < 4; ++r) inv[r] = 1.0f / l_i[r];
  const int row0 = qt * 64 + w * 16 + quad * 4;
#pragma unroll
  for (int t = 0; t < 8; ++t)
#pragma unroll
    for (int r = 0; r < 4; ++r)
      O[(b * S_LEN + row0 + r) * 2048 + h * HDIM + t * 16 + l15] =
          (__bf16)(o_acc[t][r] * inv[r]);
}

// ---------------------------------------------------------------- launch
extern "C" void kernel_launch(void* const* d_in, const int* in_sizes, int n_in,
                              void* d_out, int out_size, void* d_ws, size_t ws_size,
                              hipStream_t stream) {
  const float* hs   = (const float*)d_in[0];   // (2,2048,2048)
  const float* cosp = (const float*)d_in[1];   // (2048,128)
  const float* sinp = (const float*)d_in[2];   // (2048,128)
  const float* wqkv = (const float*)d_in[3];   // (6144,2048)
  const float* wo   = (const float*)d_in[4];   // (2048,2048)
  float* out = (float*)d_out;

  char* ws = (char*)d_ws;
  // layout: Xb 16.78MB | Wqb 25.17MB | Wob 8.39MB | QKV 50.33MB  (total 96 MiB)
  __bf16* Xb   = (__bf16*)(ws);
  __bf16* Wqb  = (__bf16*)(ws + 16777216);
  __bf16* Wob  = (__bf16*)(ws + 41943040);
  __bf16* QKV  = (__bf16*)(ws + 50331648);
  __bf16* Obuf = Xb;   // X dead after QKV GEMM; reuse for attention output
  if (ws_size < 100663296) return;

  cvt_f32_bf16<<<8192, 256, 0, stream>>>(hs, Xb, 8388608);
  cvt_f32_bf16<<<12288, 256, 0, stream>>>(wqkv, Wqb, 12582912);
  cvt_f32_bf16<<<4096, 256, 0, stream>>>(wo, Wob, 4194304);

  gemm_bt<__bf16><<<dim3(48, 32), 256, 0, stream>>>(Xb, Wqb, QKV, 4096, 6144, 2048);
  rope_kernel<<<32768, 256, 0, stream>>>(QKV, cosp, sinp);
  attn_kernel<<<dim3(32, 32), 256, 0, stream>>>(QKV, Obuf);
  gemm_bt<float><<<dim3(16, 32), 256, 0, stream>>>(Obuf, Wob, out, 4096, 2048, 2048);
}